// Round 14
// baseline (278.088 us; speedup 1.0000x reference)
//
#include <hip/hip_runtime.h>
#include <math.h>

// ---------- helpers ----------
__device__ __forceinline__ ushort f2bf(float f) {
    unsigned int u = __float_as_uint(f);
    u += 0x7FFFu + ((u >> 16) & 1u);   // round-to-nearest-even
    return (ushort)(u >> 16);
}

typedef __attribute__((address_space(1))) const unsigned int guint;
typedef __attribute__((address_space(3))) unsigned int luint;
__device__ __forceinline__ void gload_lds16(const void* g, void* l) {
    __builtin_amdgcn_global_load_lds((guint*)g, (luint*)l, 16, 0, 0);
}

template<int N>
__device__ __forceinline__ void waitvm() {
    if constexpr (N == 0)      asm volatile("s_waitcnt vmcnt(0)" ::: "memory");
    else if constexpr (N == 3) asm volatile("s_waitcnt vmcnt(3)" ::: "memory");
    else if constexpr (N == 4) asm volatile("s_waitcnt vmcnt(4)" ::: "memory");
    else                       asm volatile("s_waitcnt vmcnt(6)" ::: "memory");
}

using bfrag = __attribute__((ext_vector_type(8))) short;   // 8 bf16 = 4 VGPR
using f4    = __attribute__((ext_vector_type(4))) float;

__device__ __forceinline__ void bf8_to_f(uint4 v, float* o) {
    unsigned int u[4] = {v.x, v.y, v.z, v.w};
    #pragma unroll
    for (int i = 0; i < 4; ++i) {
        o[2 * i]     = __uint_as_float(u[i] << 16);
        o[2 * i + 1] = __uint_as_float(u[i] & 0xFFFF0000u);
    }
}

// ---------- shared xs body: NHWC bf16 of (x + up2(prev)) ----------
__device__ __forceinline__ void xs_body(void* smem,
    const float* __restrict__ x, const float* __restrict__ prev,
    ushort* __restrict__ xs, int H, int W, int bx, int by, int bz)
{
    ushort (*tile)[72] = (ushort(*)[72])smem;
    const int HW = H * W, W2 = W >> 1;
    int b = bz, c0 = by * 32, hw0 = bx * 64;
    const float* xb = x + ((size_t)b * 256 + c0) * HW;
    const float* pb = prev ? prev + ((size_t)b * 256 + c0) * (HW >> 2) : nullptr;

    int hwl = threadIdx.x & 63, cl0 = threadIdx.x >> 6;
    int hw = hw0 + hwl;
    bool ok = hw < HW;
    int hwc = ok ? hw : HW - 1;
    int h = hwc / W, w = hwc - h * W;
    int pidx = (h >> 1) * W2 + (w >> 1);
    #pragma unroll
    for (int p = 0; p < 8; ++p) {
        int cl = p * 4 + cl0;
        float v = 0.f;
        if (ok) {
            v = xb[(size_t)cl * HW + hw];
            if (pb) v += pb[(size_t)cl * (HW >> 2) + pidx];
        }
        tile[cl][hwl] = f2bf(v);
    }
    __syncthreads();
    int hwl2 = threadIdx.x >> 2, cc = (threadIdx.x & 3) * 8;
    int hw2 = hw0 + hwl2;
    if (hw2 < HW) {
        ushort vals[8];
        #pragma unroll
        for (int j = 0; j < 8; ++j) vals[j] = tile[cc + j][hwl2];
        *(uint4*)&xs[((size_t)b * HW + hw2) * 256 + c0 + cc] = *(uint4*)vals;
    }
}

// ---------- prolog: flat 1-D exact decomposition (1997 blocks) ----------
struct ProArgs {
    const float* wsrc[7];
    ushort*      wdst[7];
    float*       outp[3];      // lvl1..3 bias-prefill targets
    const float* bias[3];
    float*       zbase;
    int          z4;
    const float* x3;
    ushort*      xs3;
};
__global__ __launch_bounds__(256) void prolog_kernel(ProArgs a) {
    __shared__ __align__(16) char smem[18432];
    const int tid = threadIdx.x;
    int vb = blockIdx.x;
    if (vb < 277) {
        const float* src; ushort* dst; int M, m0;
        if (vb < 256) { src = a.wsrc[vb >> 6]; dst = a.wdst[vb >> 6]; M = 256; m0 = (vb & 63) * 4; }
        else { int u = vb - 256; src = a.wsrc[4 + u / 7]; dst = a.wdst[4 + u / 7]; M = 27; m0 = (u % 7) * 4; }
        ushort* lt = (ushort*)smem;
        #pragma unroll
        for (int i = 0; i < 9; ++i) {
            int fi = i * 256 + tid;
            if (m0 + fi / 576 < M) {
                float4 v = *(const float4*)(src + ((size_t)m0 * 2304 + (size_t)fi * 4));
                lt[fi * 4 + 0] = f2bf(v.x); lt[fi * 4 + 1] = f2bf(v.y);
                lt[fi * 4 + 2] = f2bf(v.z); lt[fi * 4 + 3] = f2bf(v.w);
            }
        }
        __syncthreads();
        for (int ch = tid; ch < 1152; ch += 256) {
            int m4 = ch / 288, rem = ch - m4 * 288;
            int r = rem >> 5, c8 = rem & 31;
            int m = m0 + m4;
            if (m < M) {
                ushort vals[8];
                #pragma unroll
                for (int j = 0; j < 8; ++j) vals[j] = lt[m4 * 2304 + (c8 * 8 + j) * 9 + r];
                *(uint4*)&dst[(size_t)m * 2304 + r * 256 + c8 * 8] = *(uint4*)vals;
            }
        }
    } else if (vb < 1789) {
        float* op; const float* bp; int HW, base;
        if (vb < 1429)      { op = a.outp[0]; bp = a.bias[0]; HW = 2304; base = vb - 277; }
        else if (vb < 1717) { op = a.outp[1]; bp = a.bias[1]; HW = 576;  base = vb - 1429; }
        else                { op = a.outp[2]; bp = a.bias[2]; HW = 144;  base = vb - 1717; }
        int i = base * 256 + tid;
        if (i < 128 * HW) {
            int e = i << 2;
            int m = (e / HW) & 255;
            float v = bp[m];
            *(float4*)&op[e] = float4{v, v, v, v};
        }
    } else if (vb < 1949) {
        int i = (vb - 1789) * 256 + tid;
        if (i < a.z4) ((float4*)a.zbase)[i] = float4{0.f, 0.f, 0.f, 0.f};
    } else {
        int v = vb - 1949;
        xs_body(smem, a.x3, nullptr, a.xs3, 12, 12, v % 3, (v / 3) & 7, v / 24);
    }
}

// ---------- xs kernel (levels 2,1,0) ----------
__global__ __launch_bounds__(256) void xs_nhwc(
    const float* __restrict__ x, const float* __restrict__ prev,
    ushort* __restrict__ xs, int H, int W)
{
    __shared__ __align__(16) char smem[32 * 72 * 2];
    xs_body(smem, x, prev, xs, H, W, blockIdx.x, blockIdx.y, blockIdx.z);
}

// ---------- deformable sampling (NHWC) -> cols[b][hw][r*256+c] bf16 ----------
__global__ __launch_bounds__(256) void sampling_kernel(
    const ushort* __restrict__ xs, const float* __restrict__ off,
    const float* __restrict__ ob, ushort* __restrict__ cols,
    int H, int W)
{
    __shared__ float4 gw[8][9];
    __shared__ int4   go[8][9];
    const int HW = H * W;
    const int b = blockIdx.z;
    const int hw0 = blockIdx.x * 8;
    const int tid = threadIdx.x;
    const float* offb = off + (size_t)b * 27 * HW;
    const ushort* xb = xs + (size_t)b * HW * 256;

    if (tid < 72) {
        int hwl = tid / 9, k = tid - hwl * 9;
        int hw = hw0 + hwl; if (hw >= HW) hw = HW - 1;
        int h = hw / W, w = hw - h * W;
        float dy = offb[(size_t)(2 * k) * HW + hw] + ob[2 * k];
        float dx = offb[(size_t)(2 * k + 1) * HW + hw] + ob[2 * k + 1];
        float mv = offb[(size_t)(18 + k) * HW + hw] + ob[18 + k];
        float mk = 1.0f / (1.0f + __expf(-mv));
        float py = (float)h - 1.0f + (float)(k / 3) + dy;
        float px = (float)w - 1.0f + (float)(k % 3) + dx;
        float y0f = floorf(py), x0f = floorf(px);
        float wy = py - y0f, wx = px - x0f;
        int y0 = (int)y0f, x0i = (int)x0f;
        int y1 = y0 + 1, x1 = x0i + 1;
        bool vy0 = (y0 >= 0) & (y0 < H), vy1 = (y1 >= 0) & (y1 < H);
        bool vx0 = (x0i >= 0) & (x0i < W), vx1 = (x1 >= 0) & (x1 < W);
        float w00 = (1.f - wy) * (1.f - wx) * ((vy0 & vx0) ? mk : 0.f);
        float w01 = (1.f - wy) * wx        * ((vy0 & vx1) ? mk : 0.f);
        float w10 = wy * (1.f - wx)        * ((vy1 & vx0) ? mk : 0.f);
        float w11 = wy * wx                * ((vy1 & vx1) ? mk : 0.f);
        int cy0 = min(max(y0, 0), H - 1), cy1 = min(max(y1, 0), H - 1);
        int cx0 = min(max(x0i, 0), W - 1), cx1 = min(max(x1, 0), W - 1);
        gw[hwl][k] = float4{w00, w01, w10, w11};
        go[hwl][k] = int4{(cy0 * W + cx0) << 8, (cy0 * W + cx1) << 8,
                          (cy1 * W + cx0) << 8, (cy1 * W + cx1) << 8};
    }
    __syncthreads();

    int hwl = tid >> 5, cb = (tid & 31) * 8;
    int hw = hw0 + hwl;
    if (hw >= HW) return;
    ushort* colp = cols + ((size_t)b * HW + hw) * 2304 + cb;

    #pragma unroll
    for (int k = 0; k < 9; ++k) {
        float4 wv = gw[hwl][k];
        int4   ov = go[hwl][k];
        float f00[8], f01[8], f10[8], f11[8];
        bf8_to_f(*(const uint4*)(xb + ov.x + cb), f00);
        bf8_to_f(*(const uint4*)(xb + ov.y + cb), f01);
        bf8_to_f(*(const uint4*)(xb + ov.z + cb), f10);
        bf8_to_f(*(const uint4*)(xb + ov.w + cb), f11);
        unsigned int pk[4];
        #pragma unroll
        for (int t = 0; t < 4; ++t) {
            float lo = f00[2 * t] * wv.x + f01[2 * t] * wv.y +
                       f10[2 * t] * wv.z + f11[2 * t] * wv.w;
            float hi = f00[2 * t + 1] * wv.x + f01[2 * t + 1] * wv.y +
                       f10[2 * t + 1] * wv.z + f11[2 * t + 1] * wv.w;
            pk[t] = (unsigned int)f2bf(lo) | ((unsigned int)f2bf(hi) << 16);
        }
        *(uint4*)(colp + k * 256) = make_uint4(pk[0], pk[1], pk[2], pk[3]);
    }
}

// ---------- bf16 MFMA GEMM: tile BMm x 64n, BK=64, TRIPLE-buffered ----------
// 3 LDS buffers -> stage(it+2) writes buf[(it+2)%3] = buf[(it-1)%3], whose
// reads were consumed before every wave passed barrier(it) (MFMA issue forces
// the compiler's lgkmcnt wait). So the mid-iteration lgkmcnt(0) + read-release
// barrier are GONE: ONE barrier/iter, and the compiler interleaves ds_read
// with MFMA using fine-grained lgkmcnt (the documented near-optimal schedule).
// RAW safety: waitvm<S> before barrier(it) drains every wave's stage(it).
template<bool IMPLICIT, bool SPLITK, int BM, int MT, int MO>
__global__ __launch_bounds__(256) void mfma_gemm(
    const ushort* __restrict__ A, const float* __restrict__ bias,
    const ushort* __restrict__ Bt, const ushort* __restrict__ zeros,
    float* __restrict__ outp, int N, int H, int W, int kchunk)
{
    constexpr int AL = BM / 32;          // A stage loads per thread
    constexpr int AI = BM / 32;          // acc rows per wave (wave m = BM/2)
    constexpr int S  = AL + 2;           // gload_lds instrs per thread per stage
    __shared__ __align__(16) ushort As[3][BM * 64];
    __shared__ __align__(16) ushort Bs[3][64 * 64];
    const int b  = blockIdx.z;
    const int m0 = (blockIdx.y % MT) * BM;
    const int kt0 = (blockIdx.y / MT) * kchunk;
    const int n0 = blockIdx.x * 64;
    const int tid  = threadIdx.x;
    const int lane = tid & 63;
    const int wv   = tid >> 6;
    const int wm = wv & 1, wn = wv >> 1;     // wave tile: (BM/2)m x 32n

    const ushort* Bb = IMPLICIT ? Bt + (size_t)b * N * 256
                                : Bt + (size_t)b * (size_t)N * 2304;

    // staging: thread i stages LDS chunk i (16B); global chunk = (i&7)^((i>>3)&7)
    const int sc8 = ((tid & 7) ^ ((tid >> 3) & 7)) * 8;
    const int srow = tid >> 3;               // 0..31
    int bn[2], bh[2], bw[2];
    #pragma unroll
    for (int j = 0; j < 2; ++j) {
        int n = n0 + j * 32 + srow; if (n >= N) n = N - 1;
        bn[j] = n; bh[j] = n / W; bw[j] = n - bh[j] * W;
    }

    auto stage = [&](int kt, int bi) {
        #pragma unroll
        for (int i = 0; i < AL; ++i) {
            gload_lds16(A + (size_t)(m0 + i * 32 + srow) * 2304 + kt + sc8,
                        (char*)As[bi] + (size_t)(i * 256 + (tid & ~63)) * 16);
        }
        if (!IMPLICIT) {
            #pragma unroll
            for (int j = 0; j < 2; ++j)
                gload_lds16(Bb + (size_t)bn[j] * 2304 + kt + sc8,
                            (char*)Bs[bi] + (size_t)(j * 256 + (tid & ~63)) * 16);
        } else {
            int r = kt >> 8, c0k = kt & 255;
            int ry = r / 3 - 1, rx = r - (r / 3) * 3 - 1;
            #pragma unroll
            for (int j = 0; j < 2; ++j) {
                int ih = bh[j] + ry, iw = bw[j] + rx;
                const ushort* src = (ih >= 0 && ih < H && iw >= 0 && iw < W)
                    ? Bb + (((size_t)(ih * W + iw)) << 8) + c0k + sc8
                    : zeros;
                gload_lds16(src, (char*)Bs[bi] + (size_t)(j * 256 + (tid & ~63)) * 16);
            }
        }
    };

    // fragment reads: row stride 64 elems (8 chunks); swizzle fv = lane&7
    const int fq = (lane >> 4);            // 0..3
    const int fv = (lane & 7);
    f4 acc[AI][2] = {};

    const int nit = kchunk >> 6;
    stage(kt0, 0);
    if (nit > 1) stage(kt0 + 64, 1);
    int bcur = 0;
    for (int it = 0; it < nit; ++it) {
        if (it + 1 < nit) waitvm<S>(); else waitvm<0>();   // stage(it) landed
        __builtin_amdgcn_s_barrier();
        __builtin_amdgcn_sched_barrier(0);
        if (it + 2 < nit) {
            int bnx = bcur + 2; if (bnx >= 3) bnx -= 3;
            stage(kt0 + (it + 2) * 64, bnx);
        }
        const ushort* as = As[bcur];
        const ushort* bs = Bs[bcur];
        bfrag af[2][AI], bf[2][2];
        #pragma unroll
        for (int kh = 0; kh < 2; ++kh) {
            int ch = ((kh * 4 + fq) ^ fv) * 8;
            #pragma unroll
            for (int i = 0; i < AI; ++i)
                af[kh][i] = *(const bfrag*)&as[(wm * (BM / 2) + i * 16 + (lane & 15)) * 64 + ch];
            #pragma unroll
            for (int j = 0; j < 2; ++j)
                bf[kh][j] = *(const bfrag*)&bs[(wn * 32 + j * 16 + (lane & 15)) * 64 + ch];
        }
        __builtin_amdgcn_s_setprio(1);
        #pragma unroll
        for (int kh = 0; kh < 2; ++kh)
            #pragma unroll
            for (int i = 0; i < AI; ++i)
                #pragma unroll
                for (int j = 0; j < 2; ++j)
                    acc[i][j] = __builtin_amdgcn_mfma_f32_16x16x32_bf16(
                        af[kh][i], bf[kh][j], acc[i][j], 0, 0, 0);
        __builtin_amdgcn_s_setprio(0);
        if (++bcur == 3) bcur = 0;
    }

    const int mb = m0 + wm * (BM / 2), nb = n0 + wn * 32;
    #pragma unroll
    for (int i = 0; i < AI; ++i) {
        int mrow = mb + i * 16 + (lane >> 4) * 4;
        #pragma unroll
        for (int j = 0; j < 2; ++j) {
            int n = nb + j * 16 + (lane & 15);
            if (n < N) {
                #pragma unroll
                for (int t = 0; t < 4; ++t) {
                    int m = mrow + t;
                    if (MO == 256 || m < MO) {
                        if (SPLITK)
                            atomicAdd(&outp[((size_t)b * MO + m) * N + n], acc[i][j][t]);
                        else
                            outp[((size_t)b * MO + m) * N + n] = acc[i][j][t] + bias[m];
                    }
                }
            }
        }
    }
}

// ---------- host launch ----------
extern "C" void kernel_launch(void* const* d_in, const int* in_sizes, int n_in,
                              void* d_out, int out_size, void* d_ws, size_t ws_size,
                              hipStream_t stream)
{
    const float* x[4]   = {(const float*)d_in[0], (const float*)d_in[1],
                           (const float*)d_in[2], (const float*)d_in[3]};
    const float* wgt[4] = {(const float*)d_in[4], (const float*)d_in[6],
                           (const float*)d_in[8], (const float*)d_in[10]};
    const float* bia[4] = {(const float*)d_in[5], (const float*)d_in[7],
                           (const float*)d_in[9], (const float*)d_in[11]};
    const float* owt[4] = {nullptr, (const float*)d_in[12],
                           (const float*)d_in[14], (const float*)d_in[16]};
    const float* obv[4] = {nullptr, (const float*)d_in[13],
                           (const float*)d_in[15], (const float*)d_in[17]};

    const int B = 2;
    const int Hs[4] = {96, 48, 24, 12};
    const int HWs[4] = {96 * 96, 48 * 48, 24 * 24, 12 * 12};

    float* out = (float*)d_out;
    size_t outOff[4];
    outOff[0] = 0;
    outOff[1] = outOff[0] + (size_t)B * 256 * HWs[0];
    outOff[2] = outOff[1] + (size_t)B * 256 * HWs[1];
    outOff[3] = outOff[2] + (size_t)B * 256 * HWs[2];

    // ---- ws carve (256B aligned)
    char* ws = (char*)d_ws;
    size_t off = 0;
    auto carve = [&](size_t bytes) { void* p = ws + off; off = (off + bytes + 255) & ~(size_t)255; return p; };
    ushort* wbf[4];
    ushort* owbf[4] = {nullptr, nullptr, nullptr, nullptr};
    for (int i = 0; i < 4; ++i) wbf[i] = (ushort*)carve((size_t)256 * 2304 * 2);
    for (int i = 1; i < 4; ++i) owbf[i] = (ushort*)carve((size_t)32 * 2304 * 2);  // pad M to 32 (BM=32 A reads)
    ushort* cols = (ushort*)carve((size_t)B * HWs[1] * 2304 * 2);   // max: level 1
    ushort* xsb[4];
    for (int i = 0; i < 4; ++i) xsb[i] = (ushort*)carve((size_t)B * 256 * HWs[i] * 2);
    int offElems = B * 27 * (HWs[1] + HWs[2] + HWs[3]);
    float* offbase = (float*)carve((size_t)offElems * 4 + 1024);
    ushort* zeros = (ushort*)(offbase + offElems);   // 1 KB zero page
    float* offbuf[4] = {nullptr,
                        offbase,
                        offbase + (size_t)B * 27 * HWs[1],
                        offbase + (size_t)B * 27 * (HWs[1] + HWs[2])};

    // ---- prolog: weight cvt + bias prefill + zero + xs3, one flat launch
    {
        ProArgs a;
        a.wsrc[0] = wgt[0]; a.wsrc[1] = wgt[1]; a.wsrc[2] = wgt[2]; a.wsrc[3] = wgt[3];
        a.wsrc[4] = owt[1]; a.wsrc[5] = owt[2]; a.wsrc[6] = owt[3];
        a.wdst[0] = wbf[0]; a.wdst[1] = wbf[1]; a.wdst[2] = wbf[2]; a.wdst[3] = wbf[3];
        a.wdst[4] = owbf[1]; a.wdst[5] = owbf[2]; a.wdst[6] = owbf[3];
        for (int i = 0; i < 3; ++i) {
            a.outp[i] = out + outOff[i + 1]; a.bias[i] = bia[i + 1];
        }
        a.zbase = offbase;
        a.z4 = (offElems * 4 + 1024) / 16;
        a.x3 = x[3];
        a.xs3 = xsb[3];
        prolog_kernel<<<dim3(1997), 256, 0, stream>>>(a);
    }

    const int oksplit[4] = {0, 6, 12, 18};  // off-conv split-K (kchunk mult of 64)
    const int ksplit[4]  = {1, 4, 6, 12};   // main-gemm split-K

    for (int lvl = 3; lvl >= 1; --lvl) {
        int H = Hs[lvl], W = H, HW = HWs[lvl];

        // offset conv: pipelined GEMM, BM=32, M=27, implicit B from xs
        {
            dim3 grd((HW + 63) / 64, oksplit[lvl], B);
            mfma_gemm<true, true, 32, 1, 27><<<grd, 256, 0, stream>>>(
                owbf[lvl], nullptr, xsb[lvl], zeros, offbuf[lvl],
                HW, H, W, 2304 / oksplit[lvl]);
        }
        // deformable sampling -> cols [b][hw][r*256+c]
        {
            dim3 grd((HW + 7) / 8, 1, B);
            sampling_kernel<<<grd, 256, 0, stream>>>(
                xsb[lvl], offbuf[lvl], obv[lvl], cols, H, W);
        }
        // main conv: split-K MFMA GEMM into bias-prefilled out
        if (lvl == 1) {
            dim3 grd((HW + 63) / 64, 2 * 4, B);
            mfma_gemm<false, true, 128, 2, 256><<<grd, 256, 0, stream>>>(
                wbf[lvl], bia[lvl], cols, zeros, out + outOff[lvl],
                HW, H, W, 2304 / 4);
        } else {
            dim3 grd((HW + 63) / 64, 4 * ksplit[lvl], B);
            mfma_gemm<false, true, 64, 4, 256><<<grd, 256, 0, stream>>>(
                wbf[lvl], bia[lvl], cols, zeros, out + outOff[lvl],
                HW, H, W, 2304 / ksplit[lvl]);
        }
        // xs for next-finer level
        {
            int Hn = Hs[lvl - 1];
            dim3 grd((HWs[lvl - 1] + 63) / 64, 8, B);
            xs_nhwc<<<grd, 256, 0, stream>>>(
                x[lvl - 1], out + outOff[lvl], xsb[lvl - 1], Hn, Hn);
        }
    }

    // level 0: implicit NHWC MFMA GEMM, direct bias write (no split-K), 128x64
    {
        dim3 grd((HWs[0] + 63) / 64, 2, 2);
        mfma_gemm<true, false, 128, 2, 256><<<grd, 256, 0, stream>>>(
            wbf[0], bia[0], xsb[0], zeros, out + outOff[0],
            HWs[0], Hs[0], Hs[0], 2304);
    }
}

// Round 15
// 240.244 us; speedup vs baseline: 1.1575x; 1.1575x over previous
//
#include <hip/hip_runtime.h>
#include <math.h>

// ---------- helpers ----------
__device__ __forceinline__ ushort f2bf(float f) {
    unsigned int u = __float_as_uint(f);
    u += 0x7FFFu + ((u >> 16) & 1u);   // round-to-nearest-even
    return (ushort)(u >> 16);
}

typedef __attribute__((address_space(1))) const unsigned int guint;
typedef __attribute__((address_space(3))) unsigned int luint;
__device__ __forceinline__ void gload_lds16(const void* g, void* l) {
    __builtin_amdgcn_global_load_lds((guint*)g, (luint*)l, 16, 0, 0);
}

template<int N>
__device__ __forceinline__ void waitvm() {
    if constexpr (N == 0)      asm volatile("s_waitcnt vmcnt(0)" ::: "memory");
    else if constexpr (N == 3) asm volatile("s_waitcnt vmcnt(3)" ::: "memory");
    else if constexpr (N == 4) asm volatile("s_waitcnt vmcnt(4)" ::: "memory");
    else                       asm volatile("s_waitcnt vmcnt(6)" ::: "memory");
}

using bfrag = __attribute__((ext_vector_type(8))) short;   // 8 bf16 = 4 VGPR
using f4    = __attribute__((ext_vector_type(4))) float;

__device__ __forceinline__ void bf8_to_f(uint4 v, float* o) {
    unsigned int u[4] = {v.x, v.y, v.z, v.w};
    #pragma unroll
    for (int i = 0; i < 4; ++i) {
        o[2 * i]     = __uint_as_float(u[i] << 16);
        o[2 * i + 1] = __uint_as_float(u[i] & 0xFFFF0000u);
    }
}

// ---------- shared xs body: NHWC bf16 of (x + up2(prev)) ----------
__device__ __forceinline__ void xs_body(void* smem,
    const float* __restrict__ x, const float* __restrict__ prev,
    ushort* __restrict__ xs, int H, int W, int bx, int by, int bz)
{
    ushort (*tile)[72] = (ushort(*)[72])smem;
    const int HW = H * W, W2 = W >> 1;
    int b = bz, c0 = by * 32, hw0 = bx * 64;
    const float* xb = x + ((size_t)b * 256 + c0) * HW;
    const float* pb = prev ? prev + ((size_t)b * 256 + c0) * (HW >> 2) : nullptr;

    int hwl = threadIdx.x & 63, cl0 = threadIdx.x >> 6;
    int hw = hw0 + hwl;
    bool ok = hw < HW;
    int hwc = ok ? hw : HW - 1;
    int h = hwc / W, w = hwc - h * W;
    int pidx = (h >> 1) * W2 + (w >> 1);
    #pragma unroll
    for (int p = 0; p < 8; ++p) {
        int cl = p * 4 + cl0;
        float v = 0.f;
        if (ok) {
            v = xb[(size_t)cl * HW + hw];
            if (pb) v += pb[(size_t)cl * (HW >> 2) + pidx];
        }
        tile[cl][hwl] = f2bf(v);
    }
    __syncthreads();
    int hwl2 = threadIdx.x >> 2, cc = (threadIdx.x & 3) * 8;
    int hw2 = hw0 + hwl2;
    if (hw2 < HW) {
        ushort vals[8];
        #pragma unroll
        for (int j = 0; j < 8; ++j) vals[j] = tile[cc + j][hwl2];
        *(uint4*)&xs[((size_t)b * HW + hw2) * 256 + c0 + cc] = *(uint4*)vals;
    }
}

// ---------- prolog: flat 1-D exact decomposition (1997 blocks) ----------
struct ProArgs {
    const float* wsrc[7];
    ushort*      wdst[7];
    float*       outp[3];      // lvl1..3 bias-prefill targets
    const float* bias[3];
    float*       zbase;
    int          z4;
    const float* x3;
    ushort*      xs3;
};
__global__ __launch_bounds__(256) void prolog_kernel(ProArgs a) {
    __shared__ __align__(16) char smem[18432];
    const int tid = threadIdx.x;
    int vb = blockIdx.x;
    if (vb < 277) {
        const float* src; ushort* dst; int M, m0;
        if (vb < 256) { src = a.wsrc[vb >> 6]; dst = a.wdst[vb >> 6]; M = 256; m0 = (vb & 63) * 4; }
        else { int u = vb - 256; src = a.wsrc[4 + u / 7]; dst = a.wdst[4 + u / 7]; M = 27; m0 = (u % 7) * 4; }
        ushort* lt = (ushort*)smem;
        #pragma unroll
        for (int i = 0; i < 9; ++i) {
            int fi = i * 256 + tid;
            if (m0 + fi / 576 < M) {
                float4 v = *(const float4*)(src + ((size_t)m0 * 2304 + (size_t)fi * 4));
                lt[fi * 4 + 0] = f2bf(v.x); lt[fi * 4 + 1] = f2bf(v.y);
                lt[fi * 4 + 2] = f2bf(v.z); lt[fi * 4 + 3] = f2bf(v.w);
            }
        }
        __syncthreads();
        for (int ch = tid; ch < 1152; ch += 256) {
            int m4 = ch / 288, rem = ch - m4 * 288;
            int r = rem >> 5, c8 = rem & 31;
            int m = m0 + m4;
            if (m < M) {
                ushort vals[8];
                #pragma unroll
                for (int j = 0; j < 8; ++j) vals[j] = lt[m4 * 2304 + (c8 * 8 + j) * 9 + r];
                *(uint4*)&dst[(size_t)m * 2304 + r * 256 + c8 * 8] = *(uint4*)vals;
            }
        }
    } else if (vb < 1789) {
        float* op; const float* bp; int HW, base;
        if (vb < 1429)      { op = a.outp[0]; bp = a.bias[0]; HW = 2304; base = vb - 277; }
        else if (vb < 1717) { op = a.outp[1]; bp = a.bias[1]; HW = 576;  base = vb - 1429; }
        else                { op = a.outp[2]; bp = a.bias[2]; HW = 144;  base = vb - 1717; }
        int i = base * 256 + tid;
        if (i < 128 * HW) {
            int e = i << 2;
            int m = (e / HW) & 255;
            float v = bp[m];
            *(float4*)&op[e] = float4{v, v, v, v};
        }
    } else if (vb < 1949) {
        int i = (vb - 1789) * 256 + tid;
        if (i < a.z4) ((float4*)a.zbase)[i] = float4{0.f, 0.f, 0.f, 0.f};
    } else {
        int v = vb - 1949;
        xs_body(smem, a.x3, nullptr, a.xs3, 12, 12, v % 3, (v / 3) & 7, v / 24);
    }
}

// ---------- xs kernel (levels 2,1,0) ----------
__global__ __launch_bounds__(256) void xs_nhwc(
    const float* __restrict__ x, const float* __restrict__ prev,
    ushort* __restrict__ xs, int H, int W)
{
    __shared__ __align__(16) char smem[32 * 72 * 2];
    xs_body(smem, x, prev, xs, H, W, blockIdx.x, blockIdx.y, blockIdx.z);
}

// ---------- deformable sampling (NHWC) -> cols[b][hw][r*256+c] bf16 ----------
__global__ __launch_bounds__(256) void sampling_kernel(
    const ushort* __restrict__ xs, const float* __restrict__ off,
    const float* __restrict__ ob, ushort* __restrict__ cols,
    int H, int W)
{
    __shared__ float4 gw[8][9];
    __shared__ int4   go[8][9];
    const int HW = H * W;
    const int b = blockIdx.z;
    const int hw0 = blockIdx.x * 8;
    const int tid = threadIdx.x;
    const float* offb = off + (size_t)b * 27 * HW;
    const ushort* xb = xs + (size_t)b * HW * 256;

    if (tid < 72) {
        int hwl = tid / 9, k = tid - hwl * 9;
        int hw = hw0 + hwl; if (hw >= HW) hw = HW - 1;
        int h = hw / W, w = hw - h * W;
        float dy = offb[(size_t)(2 * k) * HW + hw] + ob[2 * k];
        float dx = offb[(size_t)(2 * k + 1) * HW + hw] + ob[2 * k + 1];
        float mv = offb[(size_t)(18 + k) * HW + hw] + ob[18 + k];
        float mk = 1.0f / (1.0f + __expf(-mv));
        float py = (float)h - 1.0f + (float)(k / 3) + dy;
        float px = (float)w - 1.0f + (float)(k % 3) + dx;
        float y0f = floorf(py), x0f = floorf(px);
        float wy = py - y0f, wx = px - x0f;
        int y0 = (int)y0f, x0i = (int)x0f;
        int y1 = y0 + 1, x1 = x0i + 1;
        bool vy0 = (y0 >= 0) & (y0 < H), vy1 = (y1 >= 0) & (y1 < H);
        bool vx0 = (x0i >= 0) & (x0i < W), vx1 = (x1 >= 0) & (x1 < W);
        float w00 = (1.f - wy) * (1.f - wx) * ((vy0 & vx0) ? mk : 0.f);
        float w01 = (1.f - wy) * wx        * ((vy0 & vx1) ? mk : 0.f);
        float w10 = wy * (1.f - wx)        * ((vy1 & vx0) ? mk : 0.f);
        float w11 = wy * wx                * ((vy1 & vx1) ? mk : 0.f);
        int cy0 = min(max(y0, 0), H - 1), cy1 = min(max(y1, 0), H - 1);
        int cx0 = min(max(x0i, 0), W - 1), cx1 = min(max(x1, 0), W - 1);
        gw[hwl][k] = float4{w00, w01, w10, w11};
        go[hwl][k] = int4{(cy0 * W + cx0) << 8, (cy0 * W + cx1) << 8,
                          (cy1 * W + cx0) << 8, (cy1 * W + cx1) << 8};
    }
    __syncthreads();

    int hwl = tid >> 5, cb = (tid & 31) * 8;
    int hw = hw0 + hwl;
    if (hw >= HW) return;
    ushort* colp = cols + ((size_t)b * HW + hw) * 2304 + cb;

    #pragma unroll
    for (int k = 0; k < 9; ++k) {
        float4 wv = gw[hwl][k];
        int4   ov = go[hwl][k];
        float f00[8], f01[8], f10[8], f11[8];
        bf8_to_f(*(const uint4*)(xb + ov.x + cb), f00);
        bf8_to_f(*(const uint4*)(xb + ov.y + cb), f01);
        bf8_to_f(*(const uint4*)(xb + ov.z + cb), f10);
        bf8_to_f(*(const uint4*)(xb + ov.w + cb), f11);
        unsigned int pk[4];
        #pragma unroll
        for (int t = 0; t < 4; ++t) {
            float lo = f00[2 * t] * wv.x + f01[2 * t] * wv.y +
                       f10[2 * t] * wv.z + f11[2 * t] * wv.w;
            float hi = f00[2 * t + 1] * wv.x + f01[2 * t + 1] * wv.y +
                       f10[2 * t + 1] * wv.z + f11[2 * t + 1] * wv.w;
            pk[t] = (unsigned int)f2bf(lo) | ((unsigned int)f2bf(hi) << 16);
        }
        *(uint4*)(colp + k * 256) = make_uint4(pk[0], pk[1], pk[2], pk[3]);
    }
}

// ---------- bf16 MFMA GEMM: tile BMm x 64n, BK=64, counted-vmcnt pipeline ----
// Unified for main conv (BM=128/64, MO=256) and offset conv (BM=32, MT=1, MO=27).
// LDS chunk (row, c) holds global K-chunk (c ^ (row&7)); read swizzle works for
// all BM since row&7 == lane&7 in every fragment read. T5 setprio wraps the
// MFMA cluster (counted-vmcnt structure has stage/MFMA role diversity).
template<bool IMPLICIT, bool SPLITK, int BM, int MT, int MO>
__global__ __launch_bounds__(256) void mfma_gemm(
    const ushort* __restrict__ A, const float* __restrict__ bias,
    const ushort* __restrict__ Bt, const ushort* __restrict__ zeros,
    float* __restrict__ outp, int N, int H, int W, int kchunk)
{
    constexpr int AL = BM / 32;          // A stage loads per thread
    constexpr int AI = BM / 32;          // acc rows per wave (wave m = BM/2)
    constexpr int S  = AL + 2;           // gload_lds instrs per thread per stage
    __shared__ __align__(16) ushort As[2][BM * 64];
    __shared__ __align__(16) ushort Bs[2][64 * 64];
    const int b  = blockIdx.z;
    const int m0 = (blockIdx.y % MT) * BM;
    const int kt0 = (blockIdx.y / MT) * kchunk;
    const int n0 = blockIdx.x * 64;
    const int tid  = threadIdx.x;
    const int lane = tid & 63;
    const int wv   = tid >> 6;
    const int wm = wv & 1, wn = wv >> 1;     // wave tile: (BM/2)m x 32n

    const ushort* Bb = IMPLICIT ? Bt + (size_t)b * N * 256
                                : Bt + (size_t)b * (size_t)N * 2304;

    // staging: thread i stages LDS chunk i (16B); global chunk = (i&7)^((i>>3)&7)
    const int sc8 = ((tid & 7) ^ ((tid >> 3) & 7)) * 8;
    const int srow = tid >> 3;               // 0..31
    int bn[2], bh[2], bw[2];
    #pragma unroll
    for (int j = 0; j < 2; ++j) {
        int n = n0 + j * 32 + srow; if (n >= N) n = N - 1;
        bn[j] = n; bh[j] = n / W; bw[j] = n - bh[j] * W;
    }

    auto stage = [&](int kt, int bi) {
        #pragma unroll
        for (int i = 0; i < AL; ++i) {
            gload_lds16(A + (size_t)(m0 + i * 32 + srow) * 2304 + kt + sc8,
                        (char*)As[bi] + (size_t)(i * 256 + (tid & ~63)) * 16);
        }
        if (!IMPLICIT) {
            #pragma unroll
            for (int j = 0; j < 2; ++j)
                gload_lds16(Bb + (size_t)bn[j] * 2304 + kt + sc8,
                            (char*)Bs[bi] + (size_t)(j * 256 + (tid & ~63)) * 16);
        } else {
            int r = kt >> 8, c0k = kt & 255;
            int ry = r / 3 - 1, rx = r - (r / 3) * 3 - 1;
            #pragma unroll
            for (int j = 0; j < 2; ++j) {
                int ih = bh[j] + ry, iw = bw[j] + rx;
                const ushort* src = (ih >= 0 && ih < H && iw >= 0 && iw < W)
                    ? Bb + (((size_t)(ih * W + iw)) << 8) + c0k + sc8
                    : zeros;
                gload_lds16(src, (char*)Bs[bi] + (size_t)(j * 256 + (tid & ~63)) * 16);
            }
        }
    };

    // fragment reads: row stride 64 elems (8 chunks); swizzle fv = lane&7
    const int fq = (lane >> 4);            // 0..3
    const int fv = (lane & 7);
    f4 acc[AI][2] = {};

    const int nit = kchunk >> 6;
    stage(kt0, 0);
    if (nit > 1) stage(kt0 + 64, 1);
    for (int it = 0; it < nit; ++it) {
        if (it + 1 < nit) waitvm<S>(); else waitvm<0>();   // stage(it) landed
        __builtin_amdgcn_s_barrier();
        __builtin_amdgcn_sched_barrier(0);
        const ushort* as = As[it & 1];
        const ushort* bs = Bs[it & 1];
        bfrag af[2][AI], bf[2][2];
        #pragma unroll
        for (int kh = 0; kh < 2; ++kh) {
            int ch = ((kh * 4 + fq) ^ fv) * 8;
            #pragma unroll
            for (int i = 0; i < AI; ++i)
                af[kh][i] = *(const bfrag*)&as[(wm * (BM / 2) + i * 16 + (lane & 15)) * 64 + ch];
            #pragma unroll
            for (int j = 0; j < 2; ++j)
                bf[kh][j] = *(const bfrag*)&bs[(wn * 32 + j * 16 + (lane & 15)) * 64 + ch];
        }
        asm volatile("s_waitcnt lgkmcnt(0)" ::: "memory");  // frags in regs
        __builtin_amdgcn_s_barrier();                       // read-release
        __builtin_amdgcn_sched_barrier(0);
        if (it + 2 < nit) stage(kt0 + (it + 2) * 64, it & 1);
        __builtin_amdgcn_s_setprio(1);
        #pragma unroll
        for (int kh = 0; kh < 2; ++kh)
            #pragma unroll
            for (int i = 0; i < AI; ++i)
                #pragma unroll
                for (int j = 0; j < 2; ++j)
                    acc[i][j] = __builtin_amdgcn_mfma_f32_16x16x32_bf16(
                        af[kh][i], bf[kh][j], acc[i][j], 0, 0, 0);
        __builtin_amdgcn_s_setprio(0);
    }

    const int mb = m0 + wm * (BM / 2), nb = n0 + wn * 32;
    #pragma unroll
    for (int i = 0; i < AI; ++i) {
        int mrow = mb + i * 16 + (lane >> 4) * 4;
        #pragma unroll
        for (int j = 0; j < 2; ++j) {
            int n = nb + j * 16 + (lane & 15);
            if (n < N) {
                #pragma unroll
                for (int t = 0; t < 4; ++t) {
                    int m = mrow + t;
                    if (MO == 256 || m < MO) {
                        if (SPLITK)
                            atomicAdd(&outp[((size_t)b * MO + m) * N + n], acc[i][j][t]);
                        else
                            outp[((size_t)b * MO + m) * N + n] = acc[i][j][t] + bias[m];
                    }
                }
            }
        }
    }
}

// ---------- host launch ----------
extern "C" void kernel_launch(void* const* d_in, const int* in_sizes, int n_in,
                              void* d_out, int out_size, void* d_ws, size_t ws_size,
                              hipStream_t stream)
{
    const float* x[4]   = {(const float*)d_in[0], (const float*)d_in[1],
                           (const float*)d_in[2], (const float*)d_in[3]};
    const float* wgt[4] = {(const float*)d_in[4], (const float*)d_in[6],
                           (const float*)d_in[8], (const float*)d_in[10]};
    const float* bia[4] = {(const float*)d_in[5], (const float*)d_in[7],
                           (const float*)d_in[9], (const float*)d_in[11]};
    const float* owt[4] = {nullptr, (const float*)d_in[12],
                           (const float*)d_in[14], (const float*)d_in[16]};
    const float* obv[4] = {nullptr, (const float*)d_in[13],
                           (const float*)d_in[15], (const float*)d_in[17]};

    const int B = 2;
    const int Hs[4] = {96, 48, 24, 12};
    const int HWs[4] = {96 * 96, 48 * 48, 24 * 24, 12 * 12};

    float* out = (float*)d_out;
    size_t outOff[4];
    outOff[0] = 0;
    outOff[1] = outOff[0] + (size_t)B * 256 * HWs[0];
    outOff[2] = outOff[1] + (size_t)B * 256 * HWs[1];
    outOff[3] = outOff[2] + (size_t)B * 256 * HWs[2];

    // ---- ws carve (256B aligned)
    char* ws = (char*)d_ws;
    size_t off = 0;
    auto carve = [&](size_t bytes) { void* p = ws + off; off = (off + bytes + 255) & ~(size_t)255; return p; };
    ushort* wbf[4];
    ushort* owbf[4] = {nullptr, nullptr, nullptr, nullptr};
    for (int i = 0; i < 4; ++i) wbf[i] = (ushort*)carve((size_t)256 * 2304 * 2);
    for (int i = 1; i < 4; ++i) owbf[i] = (ushort*)carve((size_t)32 * 2304 * 2);  // pad M to 32 (BM=32 A reads)
    ushort* cols = (ushort*)carve((size_t)B * HWs[1] * 2304 * 2);   // max: level 1
    ushort* xsb[4];
    for (int i = 0; i < 4; ++i) xsb[i] = (ushort*)carve((size_t)B * 256 * HWs[i] * 2);
    int offElems = B * 27 * (HWs[1] + HWs[2] + HWs[3]);
    float* offbase = (float*)carve((size_t)offElems * 4 + 1024);
    ushort* zeros = (ushort*)(offbase + offElems);   // 1 KB zero page
    float* offbuf[4] = {nullptr,
                        offbase,
                        offbase + (size_t)B * 27 * HWs[1],
                        offbase + (size_t)B * 27 * (HWs[1] + HWs[2])};

    // ---- prolog: weight cvt + bias prefill + zero + xs3, one flat launch
    {
        ProArgs a;
        a.wsrc[0] = wgt[0]; a.wsrc[1] = wgt[1]; a.wsrc[2] = wgt[2]; a.wsrc[3] = wgt[3];
        a.wsrc[4] = owt[1]; a.wsrc[5] = owt[2]; a.wsrc[6] = owt[3];
        a.wdst[0] = wbf[0]; a.wdst[1] = wbf[1]; a.wdst[2] = wbf[2]; a.wdst[3] = wbf[3];
        a.wdst[4] = owbf[1]; a.wdst[5] = owbf[2]; a.wdst[6] = owbf[3];
        for (int i = 0; i < 3; ++i) {
            a.outp[i] = out + outOff[i + 1]; a.bias[i] = bia[i + 1];
        }
        a.zbase = offbase;
        a.z4 = (offElems * 4 + 1024) / 16;
        a.x3 = x[3];
        a.xs3 = xsb[3];
        prolog_kernel<<<dim3(1997), 256, 0, stream>>>(a);
    }

    const int oksplit[4] = {0, 6, 12, 18};  // off-conv split-K (kchunk mult of 64)
    const int ksplit[4]  = {1, 4, 6, 12};   // main-gemm split-K

    for (int lvl = 3; lvl >= 1; --lvl) {
        int H = Hs[lvl], W = H, HW = HWs[lvl];

        // offset conv: pipelined GEMM, BM=32, M=27, implicit B from xs
        {
            dim3 grd((HW + 63) / 64, oksplit[lvl], B);
            mfma_gemm<true, true, 32, 1, 27><<<grd, 256, 0, stream>>>(
                owbf[lvl], nullptr, xsb[lvl], zeros, offbuf[lvl],
                HW, H, W, 2304 / oksplit[lvl]);
        }
        // deformable sampling -> cols [b][hw][r*256+c]
        {
            dim3 grd((HW + 7) / 8, 1, B);
            sampling_kernel<<<grd, 256, 0, stream>>>(
                xsb[lvl], offbuf[lvl], obv[lvl], cols, H, W);
        }
        // main conv: split-K MFMA GEMM into bias-prefilled out
        if (lvl == 1) {
            dim3 grd((HW + 63) / 64, 2 * 4, B);
            mfma_gemm<false, true, 128, 2, 256><<<grd, 256, 0, stream>>>(
                wbf[lvl], bia[lvl], cols, zeros, out + outOff[lvl],
                HW, H, W, 2304 / 4);
        } else {
            dim3 grd((HW + 63) / 64, 4 * ksplit[lvl], B);
            mfma_gemm<false, true, 64, 4, 256><<<grd, 256, 0, stream>>>(
                wbf[lvl], bia[lvl], cols, zeros, out + outOff[lvl],
                HW, H, W, 2304 / ksplit[lvl]);
        }
        // xs for next-finer level
        {
            int Hn = Hs[lvl - 1];
            dim3 grd((HWs[lvl - 1] + 63) / 64, 8, B);
            xs_nhwc<<<grd, 256, 0, stream>>>(
                x[lvl - 1], out + outOff[lvl], xsb[lvl - 1], Hn, Hn);
        }
    }

    // level 0: implicit NHWC MFMA GEMM, direct bias write (no split-K), 128x64
    {
        dim3 grd((HWs[0] + 63) / 64, 2, 2);
        mfma_gemm<true, false, 128, 2, 256><<<grd, 256, 0, stream>>>(
            wbf[0], bia[0], xsb[0], zeros, out + outOff[0],
            HWs[0], Hs[0], Hs[0], 2304);
    }
}